// Round 5
// baseline (73.440 us; speedup 1.0000x reference)
//
#include <hip/hip_runtime.h>

// DCNv2 fwd — bf16-MFMA, NHWC-bf16 x, software-pipelined (1 barrier/kk).
// B=8, C=64, H=W=96, O=64, K=3, s=1, p=1, d=1, DG=1 -> Ho=Wo=96.
// R5: double-buffered samp LDS, A-frags direct-from-global (no weight LDS),
// coords prefetched 1 iter ahead, converters merged, XCD-pinned throughout.

#define B_   8
#define C_   64
#define H_   96
#define W_   96
#define O_   64
#define KK_  9
#define HW_  (H_ * W_)          // 9216
#define PIXB 64
#define NTILE (HW_ / PIXB)      // 144

typedef __attribute__((ext_vector_type(8))) short short8;   // 8 bf16
typedef __attribute__((ext_vector_type(4))) float f32x4;

__device__ __forceinline__ unsigned short f2bf(float f) {
    union { float f; unsigned u; } v; v.f = f;
    unsigned r = v.u + 0x7FFF + ((v.u >> 16) & 1);   // RNE
    return (unsigned short)(r >> 16);
}
__device__ __forceinline__ float bflo(unsigned u) {
    union { unsigned u; float f; } v; v.u = u << 16; return v.f;
}
__device__ __forceinline__ float bfhi(unsigned u) {
    union { unsigned u; float f; } v; v.u = u & 0xffff0000u; return v.f;
}
__device__ __forceinline__ unsigned packbf(float lo, float hi) {
    return (unsigned)f2bf(lo) | ((unsigned)f2bf(hi) << 16);
}

// ---- merged converter: x NCHW f32 -> NHWC bf16; blocks 0..15 also do W ----
__global__ __launch_bounds__(256)
void cvt_kernel(const float* __restrict__ x, const float* __restrict__ wgt,
                unsigned short* __restrict__ xT, unsigned short* __restrict__ wsb)
{
    __shared__ unsigned short tile[64][72];
    const int t = threadIdx.x;
    if (blockIdx.x < 16) {                       // weights: [O][C][KK] -> [kk][o][c]
        int i = blockIdx.x * 256 + t;            // 4096 = O*C
        int o = i >> 6, c = i & 63;
        #pragma unroll
        for (int kk = 0; kk < KK_; ++kk)
            wsb[kk * (O_ * C_) + o * C_ + c] =
                f2bf(wgt[(size_t)(o * C_ + c) * KK_ + kk]);
    }
    const int b  = blockIdx.x & 7;               // XCD-pinned like dcn_mfma
    const int p0 = (blockIdx.x >> 3) * 64;
    #pragma unroll
    for (int r = 0; r < 16; ++r) {
        int idx = t + 256 * r;                   // 4096 = 64c x 64p
        int c = idx >> 6, p = idx & 63;
        tile[p][c] = f2bf(x[((size_t)b * C_ + c) * HW_ + p0 + p]);
    }
    __syncthreads();
    #pragma unroll
    for (int r = 0; r < 2; ++r) {
        int idx = t + 256 * r;                   // 512 x 16 B
        int p = idx >> 3, cq = (idx & 7) * 8;
        *(uint4*)(xT + ((size_t)b * HW_ + p0 + p) * C_ + cq) =
            *(const uint4*)&tile[p][cq];
    }
}

// LDS: samp double-buffer 2 x [64 px][128 B bf16, XOR-swz] = 16384 B
//      epilogue aliases as [64 o][68 f32] = 17408 B
__global__ __launch_bounds__(256, 4)
void dcn_mfma(const unsigned short* __restrict__ xT,
              const float* __restrict__ offs, const float* __restrict__ mask,
              const unsigned short* __restrict__ wsb,
              const float* __restrict__ bias, float* __restrict__ out)
{
    __shared__ __align__(16) char lds[17536];

    const int t    = threadIdx.x;
    const int lane = t & 63;
    const int wid  = t >> 6;
    const int bi   = blockIdx.x & 7;             // XCD-pinned
    const int tile = blockIdx.x >> 3;
    const int pixbase = tile * PIXB;

    const int p_s = lane;                        // sample pixel
    const int cg  = wid;                         // channel group (16 ch)
    const int pix = pixbase + p_s;
    const int ho  = pix / W_, wo = pix % W_;
    const size_t oyb = (size_t)bi * 18 * HW_ + pix;
    const size_t mb  = (size_t)bi * 9 * HW_ + pix;
    const unsigned short* xb = xT + (size_t)bi * HW_ * C_ + cg * 16;

    const int wr = wid >> 1, wc = wid & 1;       // wave -> (o half, px half)
    const int lr = lane & 15, lg = lane >> 4;
    const int arow0 = (wr * 32 + lr) * C_ + lg * 8;        // A-frag elem offs
    const int arow1 = (wr * 32 + 16 + lr) * C_ + lg * 8;

    f32x4 acc[2][2] = {};
    short8 aM[4] = {}, aN[4] = {};

    float offy = offs[oyb], offx = offs[oyb + HW_], mv = mask[mb];

    #pragma unroll 1
    for (int kk = 0; kk < KK_; ++kk) {
        // -- prefetch coords for kk+1 (consumed next iter: full-iter cover) --
        float n_offy = 0.f, n_offx = 0.f, n_mv = 0.f;
        if (kk < KK_ - 1) {
            n_offy = offs[oyb + (size_t)(2 * kk + 2) * HW_];
            n_offx = offs[oyb + (size_t)(2 * kk + 3) * HW_];
            n_mv   = mask[mb + (size_t)(kk + 1) * HW_];
        }
        // -- prefetch A-frags(kk) from global (consumed next iter) --
        {
            const unsigned short* wsk = wsb + kk * (O_ * C_);
            aN[0] = *(const short8*)(wsk + arow0);
            aN[1] = *(const short8*)(wsk + arow1);
            aN[2] = *(const short8*)(wsk + arow0 + 32);
            aN[3] = *(const short8*)(wsk + arow1 + 32);
        }
        // -- geometry for kk, issue 8 corner loads --
        float py = (float)(ho - 1 + kk / 3) + offy;
        float px = (float)(wo - 1 + kk % 3) + offx;
        float y0f = floorf(py), x0f = floorf(px);
        float ly = py - y0f, lx = px - x0f;
        int y0 = (int)y0f, x0 = (int)x0f;
        int y1 = y0 + 1, x1 = x0 + 1;
        float hy = 1.f - ly, hx = 1.f - lx;
        bool oky0 = (y0 >= 0) & (y0 < H_), oky1 = (y1 >= 0) & (y1 < H_);
        bool okx0 = (x0 >= 0) & (x0 < W_), okx1 = (x1 >= 0) & (x1 < W_);
        float w00 = hy * hx * mv * ((oky0 & okx0) ? 1.f : 0.f);
        float w01 = hy * lx * mv * ((oky0 & okx1) ? 1.f : 0.f);
        float w10 = ly * hx * mv * ((oky1 & okx0) ? 1.f : 0.f);
        float w11 = ly * lx * mv * ((oky1 & okx1) ? 1.f : 0.f);
        int iy0 = min(max(y0, 0), H_ - 1), iy1 = min(max(y1, 0), H_ - 1);
        int ix0 = min(max(x0, 0), W_ - 1), ix1 = min(max(x1, 0), W_ - 1);
        const uint4* a00 = (const uint4*)(xb + (size_t)(iy0 * W_ + ix0) * C_);
        const uint4* a01 = (const uint4*)(xb + (size_t)(iy0 * W_ + ix1) * C_);
        const uint4* a10 = (const uint4*)(xb + (size_t)(iy1 * W_ + ix0) * C_);
        const uint4* a11 = (const uint4*)(xb + (size_t)(iy1 * W_ + ix1) * C_);
        unsigned c0[8], c1[8], c2[8], c3[8];
        *(uint4*)&c0[0] = a00[0]; *(uint4*)&c0[4] = a00[1];
        *(uint4*)&c1[0] = a01[0]; *(uint4*)&c1[4] = a01[1];
        *(uint4*)&c2[0] = a10[0]; *(uint4*)&c2[4] = a10[1];
        *(uint4*)&c3[0] = a11[0]; *(uint4*)&c3[4] = a11[1];

        // -- MFMA(kk-1) while corner loads are in flight --
        if (kk > 0) {
            const char* sb = lds + ((kk - 1) & 1) * 8192;
            #pragma unroll
            for (int ks = 0; ks < 2; ++ks) {
                int colb = ks * 64 + lg * 16;
                int rb0 = wc * 32 + lr, rb1 = rb0 + 16;
                short8 b0 = *(const short8*)(sb + rb0 * 128 + (colb ^ ((rb0 & 7) << 4)));
                short8 b1 = *(const short8*)(sb + rb1 * 128 + (colb ^ ((rb1 & 7) << 4)));
                acc[0][0] = __builtin_amdgcn_mfma_f32_16x16x32_bf16(aM[ks*2+0], b0, acc[0][0], 0, 0, 0);
                acc[0][1] = __builtin_amdgcn_mfma_f32_16x16x32_bf16(aM[ks*2+0], b1, acc[0][1], 0, 0, 0);
                acc[1][0] = __builtin_amdgcn_mfma_f32_16x16x32_bf16(aM[ks*2+1], b0, acc[1][0], 0, 0, 0);
                acc[1][1] = __builtin_amdgcn_mfma_f32_16x16x32_bf16(aM[ks*2+1], b1, acc[1][1], 0, 0, 0);
            }
        }

        // -- lerp + pack + stage samp buf[kk&1] --
        union { unsigned u[8]; uint4 v[2]; } pk;
        #pragma unroll
        for (int j = 0; j < 8; ++j) {
            float lo = fmaf(bflo(c0[j]), w00, fmaf(bflo(c1[j]), w01,
                       fmaf(bflo(c2[j]), w10, bflo(c3[j]) * w11)));
            float hi = fmaf(bfhi(c0[j]), w00, fmaf(bfhi(c1[j]), w01,
                       fmaf(bfhi(c2[j]), w10, bfhi(c3[j]) * w11)));
            pk.u[j] = packbf(lo, hi);
        }
        {
            char* sdst = lds + (kk & 1) * 8192 + p_s * 128;
            int s = (p_s & 7) << 4, cb = cg * 32;
            *(uint4*)(sdst + (cb ^ s))        = pk.v[0];
            *(uint4*)(sdst + ((cb + 16) ^ s)) = pk.v[1];
        }
        __syncthreads();
        offy = n_offy; offx = n_offx; mv = n_mv;
        aM[0] = aN[0]; aM[1] = aN[1]; aM[2] = aN[2]; aM[3] = aN[3];
    }

    // -- final MFMA on buf[(KK_-1)&1] == buf[0] --
    {
        const char* sb = lds + ((KK_ - 1) & 1) * 8192;
        #pragma unroll
        for (int ks = 0; ks < 2; ++ks) {
            int colb = ks * 64 + lg * 16;
            int rb0 = wc * 32 + lr, rb1 = rb0 + 16;
            short8 b0 = *(const short8*)(sb + rb0 * 128 + (colb ^ ((rb0 & 7) << 4)));
            short8 b1 = *(const short8*)(sb + rb1 * 128 + (colb ^ ((rb1 & 7) << 4)));
            acc[0][0] = __builtin_amdgcn_mfma_f32_16x16x32_bf16(aM[ks*2+0], b0, acc[0][0], 0, 0, 0);
            acc[0][1] = __builtin_amdgcn_mfma_f32_16x16x32_bf16(aM[ks*2+0], b1, acc[0][1], 0, 0, 0);
            acc[1][0] = __builtin_amdgcn_mfma_f32_16x16x32_bf16(aM[ks*2+1], b0, acc[1][0], 0, 0, 0);
            acc[1][1] = __builtin_amdgcn_mfma_f32_16x16x32_bf16(aM[ks*2+1], b1, acc[1][1], 0, 0, 0);
        }
    }

    // -- epilogue: LDS transpose -> float4 full-line stores --
    __syncthreads();
    float* outb = (float*)lds;                   // [64 o][68 f32]
    #pragma unroll
    for (int m = 0; m < 2; ++m) {
        int ob = wr * 32 + m * 16 + lg * 4;
        #pragma unroll
        for (int n = 0; n < 2; ++n) {
            int p = wc * 32 + n * 16 + lr;
            #pragma unroll
            for (int r = 0; r < 4; ++r)
                outb[(ob + r) * 68 + p] = acc[m][n][r];
        }
    }
    __syncthreads();
    #pragma unroll
    for (int r = 0; r < 4; ++r) {
        int idx = t + 256 * r;                   // 1024 float4 chunks
        int o = idx >> 4, pq = (idx & 15) * 4;
        float4 v = *(const float4*)&outb[o * 68 + pq];
        float bv = bias[o];
        v.x += bv; v.y += bv; v.z += bv; v.w += bv;
        *(float4*)&out[((size_t)bi * O_ + o) * HW_ + pixbase + pq] = v;
    }
}

extern "C" void kernel_launch(void* const* d_in, const int* in_sizes, int n_in,
                              void* d_out, int out_size, void* d_ws, size_t ws_size,
                              hipStream_t stream)
{
    const float* x    = (const float*)d_in[0];
    const float* offs = (const float*)d_in[1];
    const float* mask = (const float*)d_in[2];
    const float* wgt  = (const float*)d_in[3];
    const float* bias = (const float*)d_in[4];
    float* out = (float*)d_out;

    unsigned short* xT  = (unsigned short*)d_ws;                     // 9,437,184 B
    unsigned short* wsb = (unsigned short*)((char*)d_ws + 9437184);  // 73,728 B

    hipLaunchKernelGGL(cvt_kernel, dim3(B_ * NTILE), dim3(256), 0, stream,
                       x, wgt, xT, wsb);
    hipLaunchKernelGGL(dcn_mfma, dim3(B_ * NTILE), dim3(256), 0, stream,
                       xT, offs, mask, wsb, bias, out);
}

// Round 6
// 42.981 us; speedup vs baseline: 1.7087x; 1.7087x over previous
//
#include <hip/hip_runtime.h>
#include <hip/hip_bf16.h>

// DCNv2 fwd — barrier-free wave-autonomous bf16-MFMA.
// B=8, C=64, H=W=96, O=64, K=3, s=1, p=1, d=1, DG=1 -> Ho=Wo=96.
// R6: each wave owns a 64o x 16px tile; samples its own pixels into
// wave-private LDS (no __syncthreads in main loop -> prefetch survives,
// waves slip freely). Corners prefetched 1 iter ahead, coords 2 ahead.

#define B_   8
#define C_   64
#define H_   96
#define W_   96
#define O_   64
#define KK_  9
#define HW_  (H_ * W_)          // 9216
#define NTILE (HW_ / 64)        // 144

typedef __attribute__((ext_vector_type(8))) short short8;     // 8 bf16
typedef __attribute__((ext_vector_type(4))) float f32x4;
typedef __attribute__((ext_vector_type(4))) unsigned uint4v;

__device__ __forceinline__ unsigned short f2bf(float f) {
    union { float f; unsigned u; } v; v.f = f;
    unsigned r = v.u + 0x7FFF + ((v.u >> 16) & 1);   // RNE
    return (unsigned short)(r >> 16);
}
__device__ __forceinline__ float bflo(unsigned u) {
    union { unsigned u; float f; } v; v.u = u << 16; return v.f;
}
__device__ __forceinline__ float bfhi(unsigned u) {
    union { unsigned u; float f; } v; v.u = u & 0xffff0000u; return v.f;
}
__device__ __forceinline__ unsigned packbf2(float lo, float hi) {
    __hip_bfloat162 h = __float22bfloat162_rn(make_float2(lo, hi));
    union { __hip_bfloat162 h; unsigned u; } v; v.h = h; return v.u;
}

// ---- converter: x NCHW f32 -> NHWC bf16 (barrier-free, no LDS);
//      blocks 0..15 additionally emit fragment-ordered bf16 weights:
//      wsb[(((kk*2+ks)*4 + hi)*64 + o)*8 + j], c = ks*32 + hi*8 + j ----
__global__ __launch_bounds__(256)
void cvt_kernel(const float* __restrict__ x, const float* __restrict__ wgt,
                unsigned short* __restrict__ xT, unsigned short* __restrict__ wsb)
{
    const int t = threadIdx.x;
    if (blockIdx.x < 16) {
        int i = blockIdx.x * 256 + t;      // (o,c) over 4096
        int o = i >> 6, c = i & 63;
        int ks = c >> 5, hi = (c >> 3) & 3, j = c & 7;
        #pragma unroll
        for (int kk = 0; kk < KK_; ++kk)
            wsb[(size_t)(((kk*2 + ks)*4 + hi)*64 + o)*8 + j] =
                f2bf(wgt[(size_t)(o*64 + c)*KK_ + kk]);
    }
    const int b  = blockIdx.x & 7;                 // XCD-pinned
    const int px = (blockIdx.x >> 3) * 256 + t;    // 36 blk/img * 256 = 9216
    const float* xs = x + (size_t)b * C_ * HW_ + px;
    unsigned pk[32];
    #pragma unroll
    for (int c2 = 0; c2 < 32; ++c2) {
        float lo = xs[(size_t)(2*c2)   * HW_];
        float hi = xs[(size_t)(2*c2+1) * HW_];
        pk[c2] = packbf2(lo, hi);
    }
    uint4v* dst = (uint4v*)(xT + ((size_t)b * HW_ + px) * C_);
    #pragma unroll
    for (int j = 0; j < 8; ++j) {
        uint4v v;
        v.x = pk[4*j]; v.y = pk[4*j+1]; v.z = pk[4*j+2]; v.w = pk[4*j+3];
        dst[j] = v;
    }
}

// LDS: 4 waves x 2 bufs x 2048 B (16 px rows x 128 B, XOR-swizzled) = 16384
//      epilogue aliases whole lds as [64 o][68 f32] = 17408
__global__ __launch_bounds__(256, 3)
void dcn_mfma(const unsigned short* __restrict__ xT,
              const float* __restrict__ offs, const float* __restrict__ mask,
              const unsigned short* __restrict__ wsb,
              const float* __restrict__ bias, float* __restrict__ out)
{
    __shared__ __align__(16) char lds[17536];

    const int t    = threadIdx.x;
    const int lane = t & 63;
    const int wid  = t >> 6;
    const int bi   = blockIdx.x & 7;              // XCD-pinned
    const int tile = blockIdx.x >> 3;
    const int pixbase = tile * 64;

    const int lr = lane & 15, lg = lane >> 4;     // MFMA fragment coords
    const int px_s = lane >> 2;                   // sampled local px 0..15
    const int q    = lane & 3;                    // channel quarter

    const int pix = pixbase + wid * 16 + px_s;    // this lane's sample pixel
    const int ho = pix / W_, wo = pix % W_;
    const float* offp = offs + (size_t)bi * 18 * HW_ + pix;
    const float* mp   = mask + (size_t)bi * 9  * HW_ + pix;
    const unsigned short* xb = xT + (size_t)bi * HW_ * C_ + q * 16;
    char* stg = lds + wid * 4096;                 // wave-private, 2 x 2048

    f32x4 acc[4] = {};                            // 4 o-tiles x (16o x 16px)

    float coy[2], cox[2], cmv[2];
    uint4v cor[2][8];                             // 4 corners x 2 uint4
    float  cw[2][4];

    coy[0] = offp[0];          cox[0] = offp[HW_];       cmv[0] = mp[0];
    coy[1] = offp[2 * HW_];    cox[1] = offp[3 * HW_];   cmv[1] = mp[HW_];

    auto geom_issue = [&](int k, int s) {
        float py  = (float)(ho - 1 + k / 3) + coy[s];
        float pxf = (float)(wo - 1 + k % 3) + cox[s];
        float y0f = floorf(py), x0f = floorf(pxf);
        float ly = py - y0f, lx = pxf - x0f;
        int y0 = (int)y0f, x0 = (int)x0f;
        int y1 = y0 + 1, x1 = x0 + 1;
        float hy = 1.f - ly, hx = 1.f - lx;
        float mv = cmv[s];
        bool oky0 = (y0 >= 0) & (y0 < H_), oky1 = (y1 >= 0) & (y1 < H_);
        bool okx0 = (x0 >= 0) & (x0 < W_), okx1 = (x1 >= 0) & (x1 < W_);
        cw[s][0] = hy * hx * mv * ((oky0 & okx0) ? 1.f : 0.f);
        cw[s][1] = hy * lx * mv * ((oky0 & okx1) ? 1.f : 0.f);
        cw[s][2] = ly * hx * mv * ((oky1 & okx0) ? 1.f : 0.f);
        cw[s][3] = ly * lx * mv * ((oky1 & okx1) ? 1.f : 0.f);
        int iy0 = min(max(y0, 0), H_ - 1), iy1 = min(max(y1, 0), H_ - 1);
        int ix0 = min(max(x0, 0), W_ - 1), ix1 = min(max(x1, 0), W_ - 1);
        const uint4v* a00 = (const uint4v*)(xb + (size_t)(iy0 * W_ + ix0) * C_);
        const uint4v* a01 = (const uint4v*)(xb + (size_t)(iy0 * W_ + ix1) * C_);
        const uint4v* a10 = (const uint4v*)(xb + (size_t)(iy1 * W_ + ix0) * C_);
        const uint4v* a11 = (const uint4v*)(xb + (size_t)(iy1 * W_ + ix1) * C_);
        cor[s][0] = a00[0]; cor[s][1] = a00[1];
        cor[s][2] = a01[0]; cor[s][3] = a01[1];
        cor[s][4] = a10[0]; cor[s][5] = a10[1];
        cor[s][6] = a11[0]; cor[s][7] = a11[1];
    };

    geom_issue(0, 0);                             // prologue: corners(0) in flight

    #pragma unroll
    for (int kk = 0; kk < KK_; ++kk) {
        const int cur = kk & 1, nxt = cur ^ 1;

        // coords(kk+2): 2-deep prefetch (consumed by geom at iter kk+1)
        if (kk + 2 < KK_) {
            coy[cur] = offp[(size_t)(2 * kk + 4) * HW_];
            cox[cur] = offp[(size_t)(2 * kk + 5) * HW_];
            cmv[cur] = mp[(size_t)(kk + 2) * HW_];
        }
        // corners(kk+1): 1-deep prefetch (full iteration of latency cover)
        if (kk + 1 < KK_) geom_issue(kk + 1, nxt);

        // A-frags(kk): issued ~200cy before the MFMAs consume them
        short8 af[8];
        #pragma unroll
        for (int ks = 0; ks < 2; ++ks)
            #pragma unroll
            for (int m = 0; m < 4; ++m)
                af[ks * 4 + m] = *(const short8*)(wsb +
                    (size_t)((((kk * 2 + ks) * 4 + lg) * 64) + m * 16 + lr) * 8);

        // lerp corners(kk) -> bf16 pack (waits counted-vmcnt on cor[cur])
        float w00 = cw[cur][0], w01 = cw[cur][1];
        float w10 = cw[cur][2], w11 = cw[cur][3];
        uint4v pkv[2];
        #pragma unroll
        for (int j = 0; j < 8; ++j) {
            unsigned u0 = cor[cur][(j >> 2)][j & 3];
            unsigned u1 = cor[cur][2 + (j >> 2)][j & 3];
            unsigned u2 = cor[cur][4 + (j >> 2)][j & 3];
            unsigned u3 = cor[cur][6 + (j >> 2)][j & 3];
            float lo = fmaf(bflo(u0), w00, fmaf(bflo(u1), w01,
                       fmaf(bflo(u2), w10, bflo(u3) * w11)));
            float hi = fmaf(bfhi(u0), w00, fmaf(bfhi(u1), w01,
                       fmaf(bfhi(u2), w10, bfhi(u3) * w11)));
            if (j < 4) pkv[0][j & 3] = packbf2(lo, hi);
            else       pkv[1][j & 3] = packbf2(lo, hi);
        }
        // stage into wave-private buf (XOR-swizzled rows)
        {
            char* sd = stg + cur * 2048 + px_s * 128;
            int sw = (px_s & 7) << 4;
            *(uint4v*)(sd + ((q * 32) ^ sw))      = pkv[0];
            *(uint4v*)(sd + ((q * 32 + 16) ^ sw)) = pkv[1];
        }
        // B-frags + MFMA (same wave: DS pipe is in-order, no barrier needed)
        const char* sbuf = stg + cur * 2048;
        #pragma unroll
        for (int ks = 0; ks < 2; ++ks) {
            int co = ks * 64 + lg * 16;
            short8 bf = *(const short8*)(sbuf + lr * 128 + (co ^ ((lr & 7) << 4)));
            #pragma unroll
            for (int m = 0; m < 4; ++m)
                acc[m] = __builtin_amdgcn_mfma_f32_16x16x32_bf16(
                             af[ks * 4 + m], bf, acc[m], 0, 0, 0);
        }
    }

    // ---- epilogue: LDS transpose -> float4 full-line coalesced stores ----
    __syncthreads();
    float* outb = (float*)lds;                    // [64 o][68 f32]
    #pragma unroll
    for (int m = 0; m < 4; ++m)
        #pragma unroll
        for (int r = 0; r < 4; ++r)
            outb[(m * 16 + lg * 4 + r) * 68 + wid * 16 + lr] = acc[m][r];
    __syncthreads();
    #pragma unroll
    for (int r = 0; r < 4; ++r) {
        int idx = t + 256 * r;                    // 1024 float4 chunks
        int o = idx >> 4, pq = (idx & 15) * 4;
        float4 v = *(const float4*)&outb[o * 68 + pq];
        float bv = bias[o];
        v.x += bv; v.y += bv; v.z += bv; v.w += bv;
        *(float4*)&out[((size_t)bi * O_ + o) * HW_ + pixbase + pq] = v;
    }
}

extern "C" void kernel_launch(void* const* d_in, const int* in_sizes, int n_in,
                              void* d_out, int out_size, void* d_ws, size_t ws_size,
                              hipStream_t stream)
{
    const float* x    = (const float*)d_in[0];
    const float* offs = (const float*)d_in[1];
    const float* mask = (const float*)d_in[2];
    const float* wgt  = (const float*)d_in[3];
    const float* bias = (const float*)d_in[4];
    float* out = (float*)d_out;

    unsigned short* xT  = (unsigned short*)d_ws;                     // 9,437,184 B
    unsigned short* wsb = (unsigned short*)((char*)d_ws + 9437184);  // 73,728 B

    hipLaunchKernelGGL(cvt_kernel, dim3(288), dim3(256), 0, stream,
                       x, wgt, xT, wsb);
    hipLaunchKernelGGL(dcn_mfma, dim3(B_ * NTILE), dim3(256), 0, stream,
                       xT, offs, mask, wsb, bias, out);
}